// Round 1
// baseline (700.898 us; speedup 1.0000x reference)
//
#include <hip/hip_runtime.h>
#include <hip/hip_bf16.h>
#include <cstdint>

#define N_NODES 4096
#define F_IN    512
#define F_OUT   64
#define H_HEADS 8

constexpr float NEG_BIG_F = -9e15f;
constexpr float ALPHA_F   = 0.2f;

// ---------------- K0: adj int32 -> u64 bitmask per (row, 64-col chunk) ----------------
__global__ __launch_bounds__(256) void k_adj_bitmask(const int* __restrict__ adj,
                                                     unsigned long long* __restrict__ adjw) {
    int lane = threadIdx.x & 63;
    int wid  = (int)((blockIdx.x * blockDim.x + threadIdx.x) >> 6);
    int nwaves = (int)((gridDim.x * blockDim.x) >> 6);
    const int nchunks = N_NODES * (N_NODES / 64);
    for (int c = wid; c < nchunks; c += nwaves) {
        int v = adj[(size_t)c * 64 + lane];
        unsigned long long mask = __ballot(v > 0);
        if (lane == 0) adjw[c] = mask;
    }
}

// ---------------- K1: Wh[h] = x @ W[h]  (f32, LDS-tiled) ----------------
// grid: (4096/64, 8), block 256. Each block: 64 rows x 64 cols of one head.
__global__ __launch_bounds__(256) void k_wh_gemm(const float* __restrict__ x,
                                                 const float* __restrict__ W,
                                                 float* __restrict__ Wh) {
    __shared__ float xs[64][36];   // 64 rows x 32 k (pad 36 -> 144B row stride, 16B aligned)
    __shared__ float wsh[32][64];
    const int h  = blockIdx.y;
    const int rt = blockIdx.x;
    const int t  = threadIdx.x;
    const int o  = t & 63;
    const int g  = t >> 6;         // wave id: rows g*16..g*16+15

    float acc[16];
    #pragma unroll
    for (int i = 0; i < 16; i++) acc[i] = 0.f;

    const float* Wx = W + (size_t)h * F_IN * F_OUT;

    for (int k0 = 0; k0 < F_IN; k0 += 32) {
        __syncthreads();
        #pragma unroll
        for (int i = 0; i < 8; i++) {          // stage x: 64x32
            int idx = t + i * 256;
            int r = idx >> 5, kk = idx & 31;
            xs[r][kk] = x[(size_t)(rt * 64 + r) * F_IN + k0 + kk];
        }
        #pragma unroll
        for (int i = 0; i < 8; i++) {          // stage W: 32x64
            int idx = t + i * 256;
            int kk = idx >> 6, oo = idx & 63;
            wsh[kk][oo] = Wx[(size_t)(k0 + kk) * F_OUT + oo];
        }
        __syncthreads();
        #pragma unroll
        for (int k4 = 0; k4 < 8; k4++) {
            float wv0 = wsh[k4 * 4 + 0][o];
            float wv1 = wsh[k4 * 4 + 1][o];
            float wv2 = wsh[k4 * 4 + 2][o];
            float wv3 = wsh[k4 * 4 + 3][o];
            #pragma unroll
            for (int rr = 0; rr < 16; rr++) {
                int r = g * 16 + rr;
                float4 xv = *reinterpret_cast<const float4*>(&xs[r][k4 * 4]);  // wave-uniform -> broadcast
                acc[rr] = fmaf(xv.x, wv0, acc[rr]);
                acc[rr] = fmaf(xv.y, wv1, acc[rr]);
                acc[rr] = fmaf(xv.z, wv2, acc[rr]);
                acc[rr] = fmaf(xv.w, wv3, acc[rr]);
            }
        }
    }
    #pragma unroll
    for (int rr = 0; rr < 16; rr++) {
        int r = g * 16 + rr;
        Wh[((size_t)h * N_NODES + rt * 64 + r) * F_OUT + o] = acc[rr];
    }
}

// ---------------- K2: s_i / s_j per (h, n) ----------------
// one wave per row; grid = H*N/4 blocks of 256
__global__ __launch_bounds__(256) void k_scores(const float* __restrict__ Wh,
                                                const float* __restrict__ a_src,
                                                const float* __restrict__ a_tgt,
                                                float* __restrict__ s_i,
                                                float* __restrict__ s_j) {
    int lane = threadIdx.x & 63;
    int wid  = (int)((blockIdx.x * blockDim.x + threadIdx.x) >> 6);  // h*4096 + n
    int h = wid >> 12;
    float w = Wh[(size_t)wid * 64 + lane];
    float vi = w * a_src[h * 64 + lane];
    float vj = w * a_tgt[h * 64 + lane];
    #pragma unroll
    for (int m = 32; m >= 1; m >>= 1) {
        vi += __shfl_xor(vi, m, 64);
        vj += __shfl_xor(vj, m, 64);
    }
    if (lane == 0) { s_i[wid] = vi; s_j[wid] = vj; }
}

// ---------------- K3: flash-style masked softmax + PV ----------------
// grid: (4096/64, 8), block 256 (4 waves). Block: 64 rows of one head, full j sweep.
// Wave: 16 rows; lane roles: o (output col / PV) and jj (score lane) per 64-wide j-tile.
__global__ __launch_bounds__(256) void k_attn(const float* __restrict__ Wh,
                                              const float* __restrict__ s_i,
                                              const float* __restrict__ s_j,
                                              const unsigned long long* __restrict__ adjw,
                                              float* __restrict__ out) {
    __shared__ float whlds[64][64];   // Wh j-tile, [jj][o]
    const int h  = blockIdx.y;
    const int ib = blockIdx.x;
    const int t  = threadIdx.x;
    const int o  = t & 63;
    const int w  = t >> 6;
    const int row0 = ib * 64 + w * 16;

    float m[16], l[16], acc[16], si[16];
    #pragma unroll
    for (int rr = 0; rr < 16; rr++) {
        m[rr] = -INFINITY; l[rr] = 0.f; acc[rr] = 0.f;
        si[rr] = s_i[h * N_NODES + row0 + rr];
    }

    const float* WhH = Wh + (size_t)h * N_NODES * 64;
    const float* sjH = s_j + h * N_NODES;
    const unsigned long long* adjH = adjw;

    for (int jt = 0; jt < 64; jt++) {
        __syncthreads();
        #pragma unroll
        for (int i = 0; i < 16; i++) {              // stage Wh tile 64x64
            int jj = w * 16 + i;
            whlds[jj][o] = WhH[(size_t)(jt * 64 + jj) * 64 + o];
        }
        __syncthreads();

        float wh[64];                                // tile -> regs (lane = o)
        #pragma unroll
        for (int jj = 0; jj < 64; jj++) wh[jj] = whlds[jj][o];

        float sjv = sjH[jt * 64 + o];                // lane role: jj = lane

        #pragma unroll
        for (int rr = 0; rr < 16; rr++) {
            int row = row0 + rr;
            unsigned long long word = adjH[(size_t)row * 64 + jt];
            unsigned int bit = (unsigned int)(word >> o) & 1u;

            float e = si[rr] + sjv;
            e = fmaxf(e, ALPHA_F * e);               // leaky relu
            e = bit ? e : NEG_BIG_F;                 // adjacency mask

            float tm = e;                            // tile max across 64 lanes
            #pragma unroll
            for (int mm = 32; mm >= 1; mm >>= 1) tm = fmaxf(tm, __shfl_xor(tm, mm, 64));

            float mnew  = fmaxf(m[rr], tm);          // finite (>= NEG_BIG) always
            float scale = __expf(m[rr] - mnew);      // first tile: exp(-inf)=0
            float p     = __expf(e - mnew);          // masked -> exp(-9e15-m) = 0
            acc[rr] = acc[rr] * scale;
            l[rr]   = l[rr] * scale + p;             // per-lane partial sum
            m[rr]   = mnew;

            #pragma unroll
            for (int jj = 0; jj < 64; jj++) {        // PV: broadcast p via readlane
                float pv = __int_as_float(__builtin_amdgcn_readlane(__float_as_int(p), jj));
                acc[rr] = fmaf(pv, wh[jj], acc[rr]);
            }
        }
    }

    #pragma unroll
    for (int rr = 0; rr < 16; rr++) {
        float L = l[rr];
        #pragma unroll
        for (int mm = 32; mm >= 1; mm >>= 1) L += __shfl_xor(L, mm, 64);
        out[((size_t)h * N_NODES + row0 + rr) * 64 + o] = acc[rr] / L;
    }
}

// ---------------- launch ----------------
extern "C" void kernel_launch(void* const* d_in, const int* in_sizes, int n_in,
                              void* d_out, int out_size, void* d_ws, size_t ws_size,
                              hipStream_t stream) {
    const float* x     = (const float*)d_in[0];
    const int*   adj   = (const int*)d_in[1];
    const float* W     = (const float*)d_in[2];
    const float* a_src = (const float*)d_in[3];
    const float* a_tgt = (const float*)d_in[4];
    float* out = (float*)d_out;

    char* ws = (char*)d_ws;
    float* Wh  = (float*)(ws);                                   // 8*4096*64*4  = 8 MB
    float* s_i = (float*)(ws + 8388608);                         // 128 KB
    float* s_j = (float*)(ws + 8388608 + 131072);                // 128 KB
    unsigned long long* adjw = (unsigned long long*)(ws + 8388608 + 262144);  // 2 MB

    k_adj_bitmask<<<2048, 256, 0, stream>>>(adj, adjw);
    k_wh_gemm<<<dim3(N_NODES / 64, H_HEADS), 256, 0, stream>>>(x, W, Wh);
    k_scores<<<(H_HEADS * N_NODES) / 4, 256, 0, stream>>>(Wh, a_src, a_tgt, s_i, s_j);
    k_attn<<<dim3(N_NODES / 64, H_HEADS), 256, 0, stream>>>(Wh, s_i, s_j, adjw, out);
}

// Round 2
// 380.910 us; speedup vs baseline: 1.8401x; 1.8401x over previous
//
#include <hip/hip_runtime.h>
#include <hip/hip_bf16.h>
#include <cstdint>

#define N_NODES 4096
#define F_IN    512
#define F_OUT   64
#define H_HEADS 8

constexpr float NEG_BIG_F = -9e15f;
constexpr float L2E       = 1.44269504088896f;

typedef _Float16 half4_t __attribute__((ext_vector_type(4)));
typedef float    f32x4   __attribute__((ext_vector_type(4)));

__device__ inline float fast_exp2(float a) {
#if __has_builtin(__builtin_amdgcn_exp2f)
    return __builtin_amdgcn_exp2f(a);
#else
    return exp2f(a);
#endif
}

// ---------------- K0: adj int32 -> u64 bitmask per (row, 64-col chunk) ----------------
__global__ __launch_bounds__(256) void k_adj_bitmask(const int* __restrict__ adj,
                                                     unsigned long long* __restrict__ adjw) {
    int lane = threadIdx.x & 63;
    int wid  = (int)((blockIdx.x * blockDim.x + threadIdx.x) >> 6);
    int nwaves = (int)((gridDim.x * blockDim.x) >> 6);
    const int nchunks = N_NODES * (N_NODES / 64);
    for (int c = wid; c < nchunks; c += nwaves) {
        int v = adj[(size_t)c * 64 + lane];
        unsigned long long mask = __ballot(v > 0);
        if (lane == 0) adjw[c] = mask;
    }
}

// ---------------- K1: Wh = x @ W[h] (f32) + fold scores + f16 transposed write ----------------
// grid: (4096/64, 8), block 256. Block: 64 rows x 64 cols of one head.
__global__ __launch_bounds__(256) void k_wh_gemm(const float* __restrict__ x,
                                                 const float* __restrict__ W,
                                                 const float* __restrict__ a_src,
                                                 const float* __restrict__ a_tgt,
                                                 _Float16* __restrict__ WhbT,
                                                 float* __restrict__ s_i,
                                                 float* __restrict__ s_j) {
    __shared__ float xs[64][36];
    __shared__ float wsh[32][64];
    const int h  = blockIdx.y;
    const int rt = blockIdx.x;
    const int t  = threadIdx.x;
    const int o  = t & 63;
    const int g  = t >> 6;

    float acc[16];
    #pragma unroll
    for (int i = 0; i < 16; i++) acc[i] = 0.f;

    const float* Wx = W + (size_t)h * F_IN * F_OUT;

    for (int k0 = 0; k0 < F_IN; k0 += 32) {
        __syncthreads();
        #pragma unroll
        for (int i = 0; i < 8; i++) {
            int idx = t + i * 256;
            int r = idx >> 5, kk = idx & 31;
            xs[r][kk] = x[(size_t)(rt * 64 + r) * F_IN + k0 + kk];
        }
        #pragma unroll
        for (int i = 0; i < 8; i++) {
            int idx = t + i * 256;
            int kk = idx >> 6, oo = idx & 63;
            wsh[kk][oo] = Wx[(size_t)(k0 + kk) * F_OUT + oo];
        }
        __syncthreads();
        #pragma unroll
        for (int k4 = 0; k4 < 8; k4++) {
            float wv0 = wsh[k4 * 4 + 0][o];
            float wv1 = wsh[k4 * 4 + 1][o];
            float wv2 = wsh[k4 * 4 + 2][o];
            float wv3 = wsh[k4 * 4 + 3][o];
            #pragma unroll
            for (int rr = 0; rr < 16; rr++) {
                int r = g * 16 + rr;
                float4 xv = *reinterpret_cast<const float4*>(&xs[r][k4 * 4]);
                acc[rr] = fmaf(xv.x, wv0, acc[rr]);
                acc[rr] = fmaf(xv.y, wv1, acc[rr]);
                acc[rr] = fmaf(xv.z, wv2, acc[rr]);
                acc[rr] = fmaf(xv.w, wv3, acc[rr]);
            }
        }
    }

    // epilogue: scores (f32, full precision) + f16 transposed Wh
    const float as = a_src[h * 64 + o];
    const float at = a_tgt[h * 64 + o];
    _Float16 hv[16];
    #pragma unroll
    for (int rr = 0; rr < 16; rr++) {
        float vi = acc[rr] * as;
        float vj = acc[rr] * at;
        #pragma unroll
        for (int mm = 32; mm >= 1; mm >>= 1) {
            vi += __shfl_xor(vi, mm, 64);
            vj += __shfl_xor(vj, mm, 64);
        }
        if (o == 0) {
            int row = rt * 64 + g * 16 + rr;
            s_i[h * N_NODES + row] = vi;
            s_j[h * N_NODES + row] = vj;
        }
        hv[rr] = (_Float16)acc[rr];
    }
    size_t base = ((size_t)(h * 64 + o)) * N_NODES + rt * 64 + g * 16;
    *reinterpret_cast<int4*>(&WhbT[base])     = *reinterpret_cast<const int4*>(&hv[0]);
    *reinterpret_cast<int4*>(&WhbT[base + 8]) = *reinterpret_cast<const int4*>(&hv[8]);
}

// ---------------- K2: per (h,i) rowmax -> negmp = -lrelu(s_i + max_neighbor s_j) * log2(e) ----------------
// one wave per row i, all 8 heads together (adj word loaded once). grid 1024 x 256.
__global__ __launch_bounds__(256) void k_rowmax(const float* __restrict__ s_i,
                                                const float* __restrict__ s_j,
                                                const unsigned long long* __restrict__ adjw,
                                                float* __restrict__ negmp) {
    const int lane = threadIdx.x & 63;
    const int i    = (int)((blockIdx.x * blockDim.x + threadIdx.x) >> 6);

    float mx[H_HEADS];
    #pragma unroll
    for (int h = 0; h < H_HEADS; h++) mx[h] = -INFINITY;

    for (int c = 0; c < N_NODES / 64; c++) {
        unsigned long long word = adjw[(size_t)i * 64 + c];
        float addm = ((word >> lane) & 1ull) ? 0.0f : -INFINITY;
        #pragma unroll
        for (int h = 0; h < H_HEADS; h++) {
            float sj = s_j[h * N_NODES + c * 64 + lane];
            mx[h] = fmaxf(mx[h], sj + addm);
        }
    }
    #pragma unroll
    for (int h = 0; h < H_HEADS; h++) {
        float v = mx[h];
        #pragma unroll
        for (int mm = 32; mm >= 1; mm >>= 1) v = fmaxf(v, __shfl_xor(v, mm, 64));
        mx[h] = v;
    }
    if (lane == 0) {
        #pragma unroll
        for (int h = 0; h < H_HEADS; h++) {
            float e = s_i[h * N_NODES + i] + mx[h];
            e = fmaxf(e, 0.2f * e);          // lrelu (monotone => commutes with max)
            negmp[h * N_NODES + i] = -(e * L2E);
        }
    }
}

// ---------------- K3: P formation in MFMA A-layout + PV via v_mfma_f32_16x16x16f16 ----------------
// grid (4096/64, 8), block 256 (4 waves). Wave: 16 rows x 64 o-cols (4 n-tiles), sweep j.
__global__ __launch_bounds__(256) void k_attn_mfma(const _Float16* __restrict__ WhbT,
                                                   const float* __restrict__ s_i,
                                                   const float* __restrict__ negmp,
                                                   const float* __restrict__ s_j,
                                                   const unsigned long long* __restrict__ adjw,
                                                   float* __restrict__ out) {
    const int h    = blockIdx.y;
    const int t    = threadIdx.x;
    const int lane = t & 63;
    const int w    = t >> 6;
    const int i0   = blockIdx.x * 64 + w * 16;
    const int mrow = lane & 15;     // A row / B col / D col
    const int g    = lane >> 4;     // k-group

    const float si  = s_i[h * N_NODES + i0 + mrow];
    const float nmp = negmp[h * N_NODES + i0 + mrow];
    const float* __restrict__ sjh = s_j + h * N_NODES;
    const unsigned long long* __restrict__ aw = adjw + (size_t)(i0 + mrow) * 64;
    const _Float16* __restrict__ Bh = WhbT + ((size_t)h * 64 + mrow) * N_NODES;  // + ntile*16*N

    f32x4 acc0 = {0.f, 0.f, 0.f, 0.f};
    f32x4 acc1 = {0.f, 0.f, 0.f, 0.f};
    f32x4 acc2 = {0.f, 0.f, 0.f, 0.f};
    f32x4 acc3 = {0.f, 0.f, 0.f, 0.f};
    float lsum = 0.f;

    for (int c = 0; c < N_NODES / 64; c++) {
        unsigned long long word = aw[c];
        #pragma unroll
        for (int q = 0; q < 4; q++) {
            const int jb = c * 64 + q * 16;
            float4 sjv = *reinterpret_cast<const float4*>(&sjh[jb + 4 * g]);
            unsigned int nib = (unsigned int)(word >> (q * 16 + 4 * g)) & 0xFu;

            half4_t af;
            #pragma unroll
            for (int tt = 0; tt < 4; tt++) {
                float sjc = (tt == 0) ? sjv.x : (tt == 1) ? sjv.y : (tt == 2) ? sjv.z : sjv.w;
                float e = si + sjc;
                e = fmaxf(e, 0.2f * e);                       // leaky relu
                float a = fminf(fmaf(e, L2E, nmp), 0.f);      // (e - m) * log2e, clamped
                float p = fast_exp2(a);
                if (!((nib >> tt) & 1u)) p = 0.f;             // adjacency mask
                lsum += p;
                af[tt] = (_Float16)p;
            }

            const size_t bo = (size_t)jb + 4 * g;
            half4_t b0 = *reinterpret_cast<const half4_t*>(&Bh[bo]);
            half4_t b1 = *reinterpret_cast<const half4_t*>(&Bh[bo + 16 * (size_t)N_NODES]);
            half4_t b2 = *reinterpret_cast<const half4_t*>(&Bh[bo + 32 * (size_t)N_NODES]);
            half4_t b3 = *reinterpret_cast<const half4_t*>(&Bh[bo + 48 * (size_t)N_NODES]);

            acc0 = __builtin_amdgcn_mfma_f32_16x16x16f16(af, b0, acc0, 0, 0, 0);
            acc1 = __builtin_amdgcn_mfma_f32_16x16x16f16(af, b1, acc1, 0, 0, 0);
            acc2 = __builtin_amdgcn_mfma_f32_16x16x16f16(af, b2, acc2, 0, 0, 0);
            acc3 = __builtin_amdgcn_mfma_f32_16x16x16f16(af, b3, acc3, 0, 0, 0);
        }
    }

    // denominator: lane holds partial for row mrow over j in its g-quarter
    lsum += __shfl_xor(lsum, 16, 64);
    lsum += __shfl_xor(lsum, 32, 64);

    #pragma unroll
    for (int r = 0; r < 4; r++) {
        float L   = __shfl(lsum, 4 * g + r, 64);   // L for D-row 4g+r (held by lane 4g+r)
        float riv = 1.0f / L;
        int row   = i0 + 4 * g + r;
        size_t ob = ((size_t)h * N_NODES + row) * 64 + mrow;
        out[ob + 0]  = acc0[r] * riv;
        out[ob + 16] = acc1[r] * riv;
        out[ob + 32] = acc2[r] * riv;
        out[ob + 48] = acc3[r] * riv;
    }
}

// ---------------- launch ----------------
extern "C" void kernel_launch(void* const* d_in, const int* in_sizes, int n_in,
                              void* d_out, int out_size, void* d_ws, size_t ws_size,
                              hipStream_t stream) {
    const float* x     = (const float*)d_in[0];
    const int*   adj   = (const int*)d_in[1];
    const float* W     = (const float*)d_in[2];
    const float* a_src = (const float*)d_in[3];
    const float* a_tgt = (const float*)d_in[4];
    float* out = (float*)d_out;

    char* ws = (char*)d_ws;
    _Float16* WhbT = (_Float16*)(ws);                              // 4 MB: [h][o][j] f16
    float* s_i     = (float*)(ws + 4194304);                       // 128 KB
    float* s_j     = (float*)(ws + 4325376);                       // 128 KB
    float* negmp   = (float*)(ws + 4456448);                       // 128 KB
    unsigned long long* adjw = (unsigned long long*)(ws + 4587520);// 2 MB

    k_adj_bitmask<<<2048, 256, 0, stream>>>(adj, adjw);
    k_wh_gemm<<<dim3(N_NODES / 64, H_HEADS), 256, 0, stream>>>(x, W, a_src, a_tgt, WhbT, s_i, s_j);
    k_rowmax<<<1024, 256, 0, stream>>>(s_i, s_j, adjw, negmp);
    k_attn_mfma<<<dim3(N_NODES / 64, H_HEADS), 256, 0, stream>>>(WhbT, s_i, negmp, s_j, adjw, out);
}